// Round 2
// baseline (2097.173 us; speedup 1.0000x reference)
//
#include <hip/hip_runtime.h>
#include <hip/hip_bf16.h>

#define B_ 256
#define T_ 512
#define IN_ 202
#define HID_ 100
#define K_ 19

__device__ __forceinline__ float rl_f(float v, int l) {
  return __int_as_float(__builtin_amdgcn_readlane(__float_as_int(v), l));
}

// ---------------- K1: pre[row*200 + dir*100 + j] = x . w_ih^T + b_ih + b_hh
// 4 rows x 25 j per thread; W via wave-uniform loads (s_load promotion), no LDS.
__global__ __launch_bounds__(256, 3) void k_ih(
    const float* __restrict__ x,
    const float* __restrict__ wf, const float* __restrict__ wb,
    const float* __restrict__ bif, const float* __restrict__ bhf,
    const float* __restrict__ bib, const float* __restrict__ bhb,
    float* __restrict__ pre) {
  int bid = blockIdx.x;
  int dir = bid >> 9;
  int blk = bid & 511;  // 512 blocks/dir, 256 rows/block
  const float* __restrict__ w = dir ? wb : wf;
  const float* __restrict__ bi = dir ? bib : bif;
  const float* __restrict__ bh = dir ? bhb : bhf;
  int tid = threadIdx.x;
  int lane = tid & 63;
  int jg = __builtin_amdgcn_readfirstlane(tid >> 6);  // wave id -> uniform
  int j0 = jg * 25;
  long row0 = (long)blk * 256 + lane * 4;
  const float* xr = x + row0 * IN_;
  const float* wj = w + (long)j0 * IN_;
  float acc[4][25];
#pragma unroll
  for (int r = 0; r < 4; r++)
#pragma unroll
    for (int j = 0; j < 25; j++) acc[r][j] = 0.f;
  for (int kk = 0; kk < 50; kk++) {
    float4 xv[4];
#pragma unroll
    for (int r = 0; r < 4; r++)
      xv[r] = *(const float4*)(xr + r * IN_ + 4 * kk);
#pragma unroll
    for (int j = 0; j < 25; j++) {
      float4 wv = *(const float4*)(wj + j * IN_ + 4 * kk);  // uniform -> s_load
#pragma unroll
      for (int r = 0; r < 4; r++) {
        acc[r][j] += xv[r].x * wv.x + xv[r].y * wv.y + xv[r].z * wv.z + xv[r].w * wv.w;
      }
    }
  }
  {  // tail k = 200,201
    float2 xt[4];
#pragma unroll
    for (int r = 0; r < 4; r++) xt[r] = *(const float2*)(xr + r * IN_ + 200);
#pragma unroll
    for (int j = 0; j < 25; j++) {
      float2 wv = *(const float2*)(wj + j * IN_ + 200);
#pragma unroll
      for (int r = 0; r < 4; r++) acc[r][j] += xt[r].x * wv.x + xt[r].y * wv.y;
    }
  }
#pragma unroll
  for (int j = 0; j < 25; j++) {
    float bsum = bi[j0 + j] + bh[j0 + j];
#pragma unroll
    for (int r = 0; r < 4; r++) acc[r][j] += bsum;
  }
#pragma unroll
  for (int r = 0; r < 4; r++) {
    float* o = pre + (row0 + r) * 200 + dir * 100 + j0;
#pragma unroll
    for (int j = 0; j < 25; j++) o[j] = acc[r][j];
  }
}

// ---------------- K2: in-place recurrence over b (256 steps), one wave per (t,dir)
__global__ __launch_bounds__(64, 1) void k_rnn(
    float* __restrict__ pre,
    const float* __restrict__ whf, const float* __restrict__ whb) {
  int bid = blockIdx.x;
  int dir = bid >> 9;
  int t = bid & 511;
  const float* w = dir ? whb : whf;
  int lane = threadIdx.x;
  int r1 = lane + 64; if (r1 > 99) r1 = 99;  // clamped (lanes>=36 compute discarded h1)
  float w0[HID_], w1[HID_];
#pragma unroll
  for (int kk = 0; kk < 25; kk++) {
    float4 a = *(const float4*)(w + lane * HID_ + 4 * kk);
    w0[4 * kk] = a.x; w0[4 * kk + 1] = a.y; w0[4 * kk + 2] = a.z; w0[4 * kk + 3] = a.w;
    float4 b = *(const float4*)(w + r1 * HID_ + 4 * kk);
    w1[4 * kk] = b.x; w1[4 * kk + 1] = b.y; w1[4 * kk + 2] = b.z; w1[4 * kk + 3] = b.w;
  }
  int o1 = 64 + (lane < 36 ? lane : 35);
  long step = dir ? -(long)(T_ * 200) : (long)(T_ * 200);
  float* p = pre + ((long)(dir ? (B_ - 1) : 0) * T_ + t) * 200 + dir * 100;
  float h0 = 0.f, h1 = 0.f;
  float a0 = p[lane], a1 = p[o1];
  for (int s = 0; s < B_; s++) {
    float n0 = 0.f, n1 = 0.f;
    if (s < B_ - 1) { n0 = p[step + lane]; n1 = p[step + o1]; }
    float s0a = a0, s0b = 0.f, s1a = a1, s1b = 0.f;
#pragma unroll
    for (int k = 0; k < 50; k++) {
      float hk = rl_f(h0, k);
      s0a = fmaf(hk, w0[k], s0a);
      s1a = fmaf(hk, w1[k], s1a);
    }
#pragma unroll
    for (int k = 50; k < 64; k++) {
      float hk = rl_f(h0, k);
      s0b = fmaf(hk, w0[k], s0b);
      s1b = fmaf(hk, w1[k], s1b);
    }
#pragma unroll
    for (int k = 64; k < 100; k++) {
      float hk = rl_f(h1, k - 64);
      s0b = fmaf(hk, w0[k], s0b);
      s1b = fmaf(hk, w1[k], s1b);
    }
    h0 = tanhf(s0a + s0b);
    h1 = tanhf(s1a + s1b);
    p[lane] = h0;
    if (lane < 36) p[o1] = h1;
    p += step;
    a0 = n0; a1 = n1;
  }
}

// ---------------- K3: logits = h @ w_lin^T + b_lin ; softmax over 19. 2 rows/thread, no LDS.
__global__ __launch_bounds__(256, 4) void k_lin(
    const float* __restrict__ h, const float* __restrict__ wlin,
    const float* __restrict__ blin, float* __restrict__ em) {
  int tid = threadIdx.x;
  long r0 = ((long)blockIdx.x * 256 + tid) * 2;
  const float* h0 = h + r0 * 200;
  float acc0[K_], acc1[K_];
#pragma unroll
  for (int c = 0; c < K_; c++) { float bb = blin[c]; acc0[c] = bb; acc1[c] = bb; }
  for (int kk = 0; kk < 50; kk++) {
    float4 a = *(const float4*)(h0 + 4 * kk);
    float4 b = *(const float4*)(h0 + 200 + 4 * kk);
#pragma unroll
    for (int c = 0; c < K_; c++) {
      float4 wv = *(const float4*)(wlin + c * 200 + 4 * kk);  // uniform -> s_load
      acc0[c] += a.x * wv.x + a.y * wv.y + a.z * wv.z + a.w * wv.w;
      acc1[c] += b.x * wv.x + b.y * wv.y + b.z * wv.z + b.w * wv.w;
    }
  }
  float mx0 = acc0[0], mx1 = acc1[0];
#pragma unroll
  for (int c = 1; c < K_; c++) { mx0 = fmaxf(mx0, acc0[c]); mx1 = fmaxf(mx1, acc1[c]); }
  float s0 = 0.f, s1 = 0.f;
#pragma unroll
  for (int c = 0; c < K_; c++) {
    acc0[c] = __expf(acc0[c] - mx0); s0 += acc0[c];
    acc1[c] = __expf(acc1[c] - mx1); s1 += acc1[c];
  }
  float i0 = 1.f / s0, i1 = 1.f / s1;
  float* e0 = em + r0 * K_;
#pragma unroll
  for (int c = 0; c < K_; c++) { e0[c] = acc0[c] * i0; e0[K_ + c] = acc1[c] * i1; }
}

// ---------------- K4: per-b CRF logZ + gold score (wave0) | Viterbi fwd + backtrack (wave1)
// + labels written directly + deterministic last-block loss reduction.
__global__ __launch_bounds__(128, 1) void k_crf(
    const float* __restrict__ em, const int* __restrict__ y,
    const float* __restrict__ st_g, const float* __restrict__ en_g,
    const float* __restrict__ tr_g,
    float* __restrict__ part, int* __restrict__ cnt,
    float* __restrict__ out) {
  __shared__ __align__(16) float es[T_ * K_];
  __shared__ int ys[T_];
  __shared__ float tr[K_ * K_];
  __shared__ float st[K_], en[K_];
  __shared__ unsigned char hl[511 * K_ + 13];
  __shared__ float lab[T_];
  int b = blockIdx.x;
  int tid = threadIdx.x;
  const float4* eb4 = (const float4*)(em + (long)b * T_ * K_);
  for (int u = tid; u < T_ * K_ / 4; u += 128) ((float4*)es)[u] = eb4[u];
  for (int u = tid; u < T_; u += 128) ys[u] = y[b * T_ + u];
  for (int u = tid; u < K_ * K_; u += 128) tr[u] = tr_g[u];
  if (tid < K_) { st[tid] = st_g[tid]; en[tid] = en_g[tid]; }
  __syncthreads();
  int wv = tid >> 6, lane = tid & 63;
  int jj = lane < K_ ? lane : K_ - 1;
  bool act = lane < K_;
  if (wv == 0) {
    float E[K_];
#pragma unroll
    for (int i = 0; i < K_; i++) E[i] = __expf(tr[i * K_ + jj]);
    float z = act ? st[jj] + es[jj] : -1e30f;
    int y0 = ys[0];
    int prev = (y0 != -1) ? y0 : 0;
    float num = st[prev] + es[prev];
    for (int t = 1; t < T_; t++) {
      float e = es[t * K_ + jj];
      int yv = ys[t];
      bool mb = (yv != -1);
      float m = z;
#pragma unroll
      for (int off = 16; off; off >>= 1) m = fmaxf(m, __shfl_xor(m, off, 32));
      float pz = __expf(z - m);
      float acca = 0.f, accb = 0.f;
#pragma unroll
      for (int i = 0; i < 9; i++)  acca = fmaf(rl_f(pz, i), E[i], acca);
#pragma unroll
      for (int i = 9; i < K_; i++) accb = fmaf(rl_f(pz, i), E[i], accb);
      float nz = e + m + __logf(acca + accb);
      if (act && mb) z = nz;
      if (mb) {
        num += tr[prev * K_ + yv] + es[t * K_ + yv];
        prev = yv;
      }
    }
    num += en[prev];
    float zf = z + en[jj];
    float m2 = zf;
#pragma unroll
    for (int off = 16; off; off >>= 1) m2 = fmaxf(m2, __shfl_xor(m2, off, 32));
    float sm = __expf(zf - m2);
#pragma unroll
    for (int off = 16; off; off >>= 1) sm += __shfl_xor(sm, off, 32);
    if (lane == 0) part[b] = m2 + __logf(sm) - num;
  } else {
    float Tt[K_];
#pragma unroll
    for (int i = 0; i < K_; i++) Tt[i] = tr[i * K_ + jj];
    float v = act ? st[jj] + es[jj] : -1e30f;
    for (int t = 1; t < T_; t++) {
      float e = es[t * K_ + jj];
      int yv = ys[t];
      bool mb = (yv != -1);
      float b0 = -1e30f, b1 = -1e30f, b2 = -1e30f, b3 = -1e30f;
      int a0 = 0, a1 = 5, a2 = 10, a3 = 15;
#pragma unroll
      for (int i = 0; i < 5; i++)  { float c = rl_f(v, i) + Tt[i]; if (c > b0) { b0 = c; a0 = i; } }
#pragma unroll
      for (int i = 5; i < 10; i++) { float c = rl_f(v, i) + Tt[i]; if (c > b1) { b1 = c; a1 = i; } }
#pragma unroll
      for (int i = 10; i < 15; i++){ float c = rl_f(v, i) + Tt[i]; if (c > b2) { b2 = c; a2 = i; } }
#pragma unroll
      for (int i = 15; i < 19; i++){ float c = rl_f(v, i) + Tt[i]; if (c > b3) { b3 = c; a3 = i; } }
      if (b1 > b0) { b0 = b1; a0 = a1; }
      if (b2 > b0) { b0 = b2; a0 = a2; }
      if (b3 > b0) { b0 = b3; a0 = a3; }
      if (act) hl[(t - 1) * K_ + lane] = (unsigned char)a0;
      if (act && mb) v = b0 + e;
    }
    float sc = v + en[jj];
    float bb = -1e30f; int aa = 0;
#pragma unroll
    for (int i = 0; i < K_; i++) { float c = rl_f(sc, i); if (c > bb) { bb = c; aa = i; } }
    // ---- backtrack: prefetched parallel row load + readlane select (short dep chain)
    int tag = aa;
    if (lane == 0) lab[T_ - 1] = (ys[T_ - 1] != -1) ? (float)tag : -1.f;
    int vc = (lane < K_) ? (int)hl[510 * K_ + lane] : 0;
    for (int ti = 510; ti >= 0; ti--) {
      int vn = 0;
      if (ti > 0 && lane < K_) vn = (int)hl[(ti - 1) * K_ + lane];
      int ts = __builtin_amdgcn_readfirstlane(tag);
      int cand = __builtin_amdgcn_readlane(vc, ts);
      tag = (ys[ti + 1] != -1) ? cand : tag;
      if (lane == 0) lab[ti] = (ys[ti] != -1) ? (float)tag : -1.f;
      vc = vn;
    }
  }
  __syncthreads();
  if (wv == 1) {
    float* ob = out + 1 + (long)b * T_;
    for (int u = lane; u < T_; u += 64) ob[u] = lab[u];
  } else {
    int old = -1;
    if (lane == 0) { __threadfence(); old = atomicAdd(cnt, 1); }
    old = __shfl(old, 0, 64);
    if (old == B_ - 1) {  // last block to finish: deterministic fixed-order sum
      __threadfence();
      float s = 0.f;
      for (int u = lane; u < B_; u += 64) s += part[u];
#pragma unroll
      for (int off = 32; off; off >>= 1) s += __shfl_xor(s, off, 64);
      if (lane == 0) out[0] = s;
    }
  }
}

extern "C" void kernel_launch(void* const* d_in, const int* in_sizes, int n_in,
                              void* d_out, int out_size, void* d_ws, size_t ws_size,
                              hipStream_t stream) {
  const float* x      = (const float*)d_in[0];
  const int*   y      = (const int*)d_in[1];
  const float* w_ih_f = (const float*)d_in[2];
  const float* w_hh_f = (const float*)d_in[3];
  const float* b_ih_f = (const float*)d_in[4];
  const float* b_hh_f = (const float*)d_in[5];
  const float* w_ih_b = (const float*)d_in[6];
  const float* w_hh_b = (const float*)d_in[7];
  const float* b_ih_b = (const float*)d_in[8];
  const float* b_hh_b = (const float*)d_in[9];
  const float* w_lin  = (const float*)d_in[10];
  const float* b_lin  = (const float*)d_in[11];
  const float* st     = (const float*)d_in[12];
  const float* en     = (const float*)d_in[13];
  const float* trans  = (const float*)d_in[14];

  char* ws = (char*)d_ws;
  const size_t PRE_OFF  = 0;                          // 131072*200*4 = 104857600
  const size_t EM_OFF   = 104857600;                  // 131072*19*4  = 9961472
  const size_t PART_OFF = EM_OFF + 9961472;           // 1024
  const size_t CNT_OFF  = PART_OFF + 1024;            // 4
  float* PRE  = (float*)(ws + PRE_OFF);
  float* EM   = (float*)(ws + EM_OFF);
  float* PART = (float*)(ws + PART_OFF);
  int*   CNT  = (int*)(ws + CNT_OFF);
  float* out  = (float*)d_out;

  hipMemsetAsync((void*)CNT, 0, sizeof(int), stream);
  k_ih<<<1024, 256, 0, stream>>>(x, w_ih_f, w_ih_b, b_ih_f, b_hh_f, b_ih_b, b_hh_b, PRE);
  k_rnn<<<1024, 64, 0, stream>>>(PRE, w_hh_f, w_hh_b);
  k_lin<<<256, 256, 0, stream>>>(PRE, w_lin, b_lin, EM);
  k_crf<<<256, 128, 0, stream>>>(EM, y, st, en, trans, PART, CNT, out);
}

// Round 3
// 898.103 us; speedup vs baseline: 2.3351x; 2.3351x over previous
//
#include <hip/hip_runtime.h>
#include <hip/hip_bf16.h>

#define B_ 256
#define T_ 512
#define IN_ 202
#define HID_ 100
#define K_ 19

__device__ __forceinline__ float rl_f(float v, int l) {
  return __int_as_float(__builtin_amdgcn_readlane(__float_as_int(v), l));
}

// ---------------- K1: pre[row*200 + c] = x . [wf;wb]^T + bias, both dirs fused.
// Tile: 128 rows x 200 cols per block; 256 threads = 32 rowgrps(4 rows) x 8 colgrps(25 cols).
// K staged in LDS in chunks of 32 (zero-padded tail). Register-tiled: 4x25 acc.
__global__ __launch_bounds__(256, 2) void k_ih(
    const float* __restrict__ x,
    const float* __restrict__ wf, const float* __restrict__ wb,
    const float* __restrict__ bif, const float* __restrict__ bhf,
    const float* __restrict__ bib, const float* __restrict__ bhb,
    float* __restrict__ pre) {
  __shared__ float2 xs[128][17];   // [row][kpair], stride 17 f2 = 34 f -> conflict-free reads
  __shared__ float2 wsm[200][17];  // [col][kpair]
  __shared__ float bsum[200];
  int tid = threadIdx.x;
  int cg = tid & 7, rg = tid >> 3;
  int c0 = cg * 25;
  int rowbase = rg * 4;
  long row0 = (long)blockIdx.x * 128;
  for (int u = tid; u < 200; u += 256)
    bsum[u] = (u < 100) ? (bif[u] + bhf[u]) : (bib[u - 100] + bhb[u - 100]);
  float acc[4][25];
#pragma unroll
  for (int r = 0; r < 4; r++)
#pragma unroll
    for (int j = 0; j < 25; j++) acc[r][j] = 0.f;

  for (int ck = 0; ck < 7; ck++) {
    int k0 = ck * 32;
    __syncthreads();
    // stage x: 128 rows x 16 float2, coalesced
    for (int u = tid; u < 2048; u += 256) {
      int r = u >> 4, kp = u & 15;
      int gk = k0 + 2 * kp;
      float2 v = make_float2(0.f, 0.f);
      if (gk < IN_) v = *(const float2*)(x + (row0 + r) * IN_ + gk);
      xs[r][kp] = v;
    }
    // stage w: 200 cols x 16 float2, coalesced
    for (int u = tid; u < 3200; u += 256) {
      int c = u >> 4, kp = u & 15;
      int gk = k0 + 2 * kp;
      float2 v = make_float2(0.f, 0.f);
      if (gk < IN_) {
        const float* src = (c < 100) ? (wf + c * IN_) : (wb + (c - 100) * IN_);
        v = *(const float2*)(src + gk);
      }
      wsm[c][kp] = v;
    }
    __syncthreads();
#pragma unroll 4
    for (int kk = 0; kk < 16; kk++) {
      float2 xv0 = xs[rowbase + 0][kk];
      float2 xv1 = xs[rowbase + 1][kk];
      float2 xv2 = xs[rowbase + 2][kk];
      float2 xv3 = xs[rowbase + 3][kk];
#pragma unroll
      for (int j = 0; j < 25; j++) {
        float2 wv = wsm[c0 + j][kk];
        acc[0][j] = fmaf(xv0.y, wv.y, fmaf(xv0.x, wv.x, acc[0][j]));
        acc[1][j] = fmaf(xv1.y, wv.y, fmaf(xv1.x, wv.x, acc[1][j]));
        acc[2][j] = fmaf(xv2.y, wv.y, fmaf(xv2.x, wv.x, acc[2][j]));
        acc[3][j] = fmaf(xv3.y, wv.y, fmaf(xv3.x, wv.x, acc[3][j]));
      }
    }
  }
#pragma unroll
  for (int rr = 0; rr < 4; rr++) {
    float* o = pre + (row0 + rowbase + rr) * 200 + c0;
#pragma unroll
    for (int j = 0; j < 25; j++) o[j] = acc[rr][j] + bsum[c0 + j];
  }
}

// ---------------- K2: in-place recurrence over b (256 steps), one wave per (t,dir)
__global__ __launch_bounds__(64, 1) void k_rnn(
    float* __restrict__ pre,
    const float* __restrict__ whf, const float* __restrict__ whb) {
  int bid = blockIdx.x;
  int dir = bid >> 9;
  int t = bid & 511;
  const float* w = dir ? whb : whf;
  int lane = threadIdx.x;
  int r1 = lane + 64; if (r1 > 99) r1 = 99;  // clamped (lanes>=36 compute discarded h1)
  float w0[HID_], w1[HID_];
#pragma unroll
  for (int kk = 0; kk < 25; kk++) {
    float4 a = *(const float4*)(w + lane * HID_ + 4 * kk);
    w0[4 * kk] = a.x; w0[4 * kk + 1] = a.y; w0[4 * kk + 2] = a.z; w0[4 * kk + 3] = a.w;
    float4 b = *(const float4*)(w + r1 * HID_ + 4 * kk);
    w1[4 * kk] = b.x; w1[4 * kk + 1] = b.y; w1[4 * kk + 2] = b.z; w1[4 * kk + 3] = b.w;
  }
  int o1 = 64 + (lane < 36 ? lane : 35);
  long step = dir ? -(long)(T_ * 200) : (long)(T_ * 200);
  float* p = pre + ((long)(dir ? (B_ - 1) : 0) * T_ + t) * 200 + dir * 100;
  float h0 = 0.f, h1 = 0.f;
  float a0 = p[lane], a1 = p[o1];
  for (int s = 0; s < B_; s++) {
    float n0 = 0.f, n1 = 0.f;
    if (s < B_ - 1) { n0 = p[step + lane]; n1 = p[step + o1]; }
    float s0a = a0, s0b = 0.f, s1a = a1, s1b = 0.f;
#pragma unroll
    for (int k = 0; k < 50; k++) {
      float hk = rl_f(h0, k);
      s0a = fmaf(hk, w0[k], s0a);
      s1a = fmaf(hk, w1[k], s1a);
    }
#pragma unroll
    for (int k = 50; k < 64; k++) {
      float hk = rl_f(h0, k);
      s0b = fmaf(hk, w0[k], s0b);
      s1b = fmaf(hk, w1[k], s1b);
    }
#pragma unroll
    for (int k = 64; k < 100; k++) {
      float hk = rl_f(h1, k - 64);
      s0b = fmaf(hk, w0[k], s0b);
      s1b = fmaf(hk, w1[k], s1b);
    }
    h0 = tanhf(s0a + s0b);
    h1 = tanhf(s1a + s1b);
    p[lane] = h0;
    if (lane < 36) p[o1] = h1;
    p += step;
    a0 = n0; a1 = n1;
  }
}

// ---------------- K3: logits = h @ w_lin^T + b_lin ; softmax over 19. 2 rows/thread.
__global__ __launch_bounds__(256, 4) void k_lin(
    const float* __restrict__ h, const float* __restrict__ wlin,
    const float* __restrict__ blin, float* __restrict__ em) {
  int tid = threadIdx.x;
  long r0 = ((long)blockIdx.x * 256 + tid) * 2;
  const float* h0 = h + r0 * 200;
  float acc0[K_], acc1[K_];
#pragma unroll
  for (int c = 0; c < K_; c++) { float bb = blin[c]; acc0[c] = bb; acc1[c] = bb; }
  for (int kk = 0; kk < 50; kk++) {
    float4 a = *(const float4*)(h0 + 4 * kk);
    float4 b = *(const float4*)(h0 + 200 + 4 * kk);
#pragma unroll
    for (int c = 0; c < K_; c++) {
      float4 wv = *(const float4*)(wlin + c * 200 + 4 * kk);  // uniform -> s_load
      acc0[c] += a.x * wv.x + a.y * wv.y + a.z * wv.z + a.w * wv.w;
      acc1[c] += b.x * wv.x + b.y * wv.y + b.z * wv.z + b.w * wv.w;
    }
  }
  float mx0 = acc0[0], mx1 = acc1[0];
#pragma unroll
  for (int c = 1; c < K_; c++) { mx0 = fmaxf(mx0, acc0[c]); mx1 = fmaxf(mx1, acc1[c]); }
  float s0 = 0.f, s1 = 0.f;
#pragma unroll
  for (int c = 0; c < K_; c++) {
    acc0[c] = __expf(acc0[c] - mx0); s0 += acc0[c];
    acc1[c] = __expf(acc1[c] - mx1); s1 += acc1[c];
  }
  float i0 = 1.f / s0, i1 = 1.f / s1;
  float* e0 = em + r0 * K_;
#pragma unroll
  for (int c = 0; c < K_; c++) { e0[c] = acc0[c] * i0; e0[K_ + c] = acc1[c] * i1; }
}

// ---------------- K4: per-b CRF logZ + gold score (wave0) | Viterbi fwd + backtrack (wave1)
__global__ __launch_bounds__(128, 1) void k_crf(
    const float* __restrict__ em, const int* __restrict__ y,
    const float* __restrict__ st_g, const float* __restrict__ en_g,
    const float* __restrict__ tr_g,
    float* __restrict__ part, int* __restrict__ cnt,
    float* __restrict__ out) {
  __shared__ __align__(16) float es[T_ * K_];
  __shared__ int ys[T_];
  __shared__ float tr[K_ * K_];
  __shared__ float st[K_], en[K_];
  __shared__ unsigned char hl[511 * K_ + 13];
  __shared__ float lab[T_];
  int b = blockIdx.x;
  int tid = threadIdx.x;
  const float4* eb4 = (const float4*)(em + (long)b * T_ * K_);
  for (int u = tid; u < T_ * K_ / 4; u += 128) ((float4*)es)[u] = eb4[u];
  for (int u = tid; u < T_; u += 128) ys[u] = y[b * T_ + u];
  for (int u = tid; u < K_ * K_; u += 128) tr[u] = tr_g[u];
  if (tid < K_) { st[tid] = st_g[tid]; en[tid] = en_g[tid]; }
  __syncthreads();
  int wv = tid >> 6, lane = tid & 63;
  int jj = lane < K_ ? lane : K_ - 1;
  bool act = lane < K_;
  if (wv == 0) {
    float E[K_];
#pragma unroll
    for (int i = 0; i < K_; i++) E[i] = __expf(tr[i * K_ + jj]);
    float z = act ? st[jj] + es[jj] : -1e30f;
    int y0 = ys[0];
    int prev = (y0 != -1) ? y0 : 0;
    float num = st[prev] + es[prev];
    for (int t = 1; t < T_; t++) {
      float e = es[t * K_ + jj];
      int yv = ys[t];
      bool mb = (yv != -1);
      float m = z;
#pragma unroll
      for (int off = 16; off; off >>= 1) m = fmaxf(m, __shfl_xor(m, off, 32));
      float pz = __expf(z - m);
      float acca = 0.f, accb = 0.f;
#pragma unroll
      for (int i = 0; i < 9; i++)  acca = fmaf(rl_f(pz, i), E[i], acca);
#pragma unroll
      for (int i = 9; i < K_; i++) accb = fmaf(rl_f(pz, i), E[i], accb);
      float nz = e + m + __logf(acca + accb);
      if (act && mb) z = nz;
      if (mb) {
        num += tr[prev * K_ + yv] + es[t * K_ + yv];
        prev = yv;
      }
    }
    num += en[prev];
    float zf = z + en[jj];
    float m2 = zf;
#pragma unroll
    for (int off = 16; off; off >>= 1) m2 = fmaxf(m2, __shfl_xor(m2, off, 32));
    float sm = __expf(zf - m2);
#pragma unroll
    for (int off = 16; off; off >>= 1) sm += __shfl_xor(sm, off, 32);
    if (lane == 0) part[b] = m2 + __logf(sm) - num;
  } else {
    float Tt[K_];
#pragma unroll
    for (int i = 0; i < K_; i++) Tt[i] = tr[i * K_ + jj];
    float v = act ? st[jj] + es[jj] : -1e30f;
    for (int t = 1; t < T_; t++) {
      float e = es[t * K_ + jj];
      int yv = ys[t];
      bool mb = (yv != -1);
      float b0 = -1e30f, b1 = -1e30f, b2 = -1e30f, b3 = -1e30f;
      int a0 = 0, a1 = 5, a2 = 10, a3 = 15;
#pragma unroll
      for (int i = 0; i < 5; i++)  { float c = rl_f(v, i) + Tt[i]; if (c > b0) { b0 = c; a0 = i; } }
#pragma unroll
      for (int i = 5; i < 10; i++) { float c = rl_f(v, i) + Tt[i]; if (c > b1) { b1 = c; a1 = i; } }
#pragma unroll
      for (int i = 10; i < 15; i++){ float c = rl_f(v, i) + Tt[i]; if (c > b2) { b2 = c; a2 = i; } }
#pragma unroll
      for (int i = 15; i < 19; i++){ float c = rl_f(v, i) + Tt[i]; if (c > b3) { b3 = c; a3 = i; } }
      if (b1 > b0) { b0 = b1; a0 = a1; }
      if (b2 > b0) { b0 = b2; a0 = a2; }
      if (b3 > b0) { b0 = b3; a0 = a3; }
      if (act) hl[(t - 1) * K_ + lane] = (unsigned char)a0;
      if (act && mb) v = b0 + e;
    }
    float sc = v + en[jj];
    float bb = -1e30f; int aa = 0;
#pragma unroll
    for (int i = 0; i < K_; i++) { float c = rl_f(sc, i); if (c > bb) { bb = c; aa = i; } }
    int tag = aa;
    if (lane == 0) lab[T_ - 1] = (ys[T_ - 1] != -1) ? (float)tag : -1.f;
    int vc = (lane < K_) ? (int)hl[510 * K_ + lane] : 0;
    for (int ti = 510; ti >= 0; ti--) {
      int vn = 0;
      if (ti > 0 && lane < K_) vn = (int)hl[(ti - 1) * K_ + lane];
      int ts = __builtin_amdgcn_readfirstlane(tag);
      int cand = __builtin_amdgcn_readlane(vc, ts);
      tag = (ys[ti + 1] != -1) ? cand : tag;
      if (lane == 0) lab[ti] = (ys[ti] != -1) ? (float)tag : -1.f;
      vc = vn;
    }
  }
  __syncthreads();
  if (wv == 1) {
    float* ob = out + 1 + (long)b * T_;
    for (int u = lane; u < T_; u += 64) ob[u] = lab[u];
  } else {
    int old = -1;
    if (lane == 0) { __threadfence(); old = atomicAdd(cnt, 1); }
    old = __shfl(old, 0, 64);
    if (old == B_ - 1) {  // last block: deterministic fixed-order sum
      __threadfence();
      float s = 0.f;
      for (int u = lane; u < B_; u += 64) s += part[u];
#pragma unroll
      for (int off = 32; off; off >>= 1) s += __shfl_xor(s, off, 64);
      if (lane == 0) out[0] = s;
    }
  }
}

extern "C" void kernel_launch(void* const* d_in, const int* in_sizes, int n_in,
                              void* d_out, int out_size, void* d_ws, size_t ws_size,
                              hipStream_t stream) {
  const float* x      = (const float*)d_in[0];
  const int*   y      = (const int*)d_in[1];
  const float* w_ih_f = (const float*)d_in[2];
  const float* w_hh_f = (const float*)d_in[3];
  const float* b_ih_f = (const float*)d_in[4];
  const float* b_hh_f = (const float*)d_in[5];
  const float* w_ih_b = (const float*)d_in[6];
  const float* w_hh_b = (const float*)d_in[7];
  const float* b_ih_b = (const float*)d_in[8];
  const float* b_hh_b = (const float*)d_in[9];
  const float* w_lin  = (const float*)d_in[10];
  const float* b_lin  = (const float*)d_in[11];
  const float* st     = (const float*)d_in[12];
  const float* en     = (const float*)d_in[13];
  const float* trans  = (const float*)d_in[14];

  char* ws = (char*)d_ws;
  const size_t PRE_OFF  = 0;                          // 131072*200*4 = 104857600
  const size_t EM_OFF   = 104857600;                  // 131072*19*4  = 9961472
  const size_t PART_OFF = EM_OFF + 9961472;           // 1024
  const size_t CNT_OFF  = PART_OFF + 1024;            // 4
  float* PRE  = (float*)(ws + PRE_OFF);
  float* EM   = (float*)(ws + EM_OFF);
  float* PART = (float*)(ws + PART_OFF);
  int*   CNT  = (int*)(ws + CNT_OFF);
  float* out  = (float*)d_out;

  hipMemsetAsync((void*)CNT, 0, sizeof(int), stream);
  k_ih<<<1024, 256, 0, stream>>>(x, w_ih_f, w_ih_b, b_ih_f, b_hh_f, b_ih_b, b_hh_b, PRE);
  k_rnn<<<1024, 64, 0, stream>>>(PRE, w_hh_f, w_hh_b);
  k_lin<<<256, 256, 0, stream>>>(PRE, w_lin, b_lin, EM);
  k_crf<<<256, 128, 0, stream>>>(EM, y, st, en, trans, PART, CNT, out);
}

// Round 4
// 798.978 us; speedup vs baseline: 2.6248x; 1.1241x over previous
//
#include <hip/hip_runtime.h>
#include <hip/hip_bf16.h>

#define B_ 256
#define T_ 512
#define IN_ 202
#define HID_ 100
#define K_ 19

__device__ __forceinline__ float rl_f(float v, int l) {
  return __int_as_float(__builtin_amdgcn_readlane(__float_as_int(v), l));
}

// ---------------- K1: pre[row*200 + c] = x . [wf;wb]^T + bias, both dirs fused.
__global__ __launch_bounds__(256, 2) void k_ih(
    const float* __restrict__ x,
    const float* __restrict__ wf, const float* __restrict__ wb,
    const float* __restrict__ bif, const float* __restrict__ bhf,
    const float* __restrict__ bib, const float* __restrict__ bhb,
    float* __restrict__ pre) {
  __shared__ float2 xs[128][17];   // [row][kpair], stride 17 f2 = 34 f -> conflict-free reads
  __shared__ float2 wsm[200][17];  // [col][kpair]
  __shared__ float bsum[200];
  int tid = threadIdx.x;
  int cg = tid & 7, rg = tid >> 3;
  int c0 = cg * 25;
  int rowbase = rg * 4;
  long row0 = (long)blockIdx.x * 128;
  for (int u = tid; u < 200; u += 256)
    bsum[u] = (u < 100) ? (bif[u] + bhf[u]) : (bib[u - 100] + bhb[u - 100]);
  float acc[4][25];
#pragma unroll
  for (int r = 0; r < 4; r++)
#pragma unroll
    for (int j = 0; j < 25; j++) acc[r][j] = 0.f;

  for (int ck = 0; ck < 7; ck++) {
    int k0 = ck * 32;
    __syncthreads();
    for (int u = tid; u < 2048; u += 256) {
      int r = u >> 4, kp = u & 15;
      int gk = k0 + 2 * kp;
      float2 v = make_float2(0.f, 0.f);
      if (gk < IN_) v = *(const float2*)(x + (row0 + r) * IN_ + gk);
      xs[r][kp] = v;
    }
    for (int u = tid; u < 3200; u += 256) {
      int c = u >> 4, kp = u & 15;
      int gk = k0 + 2 * kp;
      float2 v = make_float2(0.f, 0.f);
      if (gk < IN_) {
        const float* src = (c < 100) ? (wf + c * IN_) : (wb + (c - 100) * IN_);
        v = *(const float2*)(src + gk);
      }
      wsm[c][kp] = v;
    }
    __syncthreads();
#pragma unroll 4
    for (int kk = 0; kk < 16; kk++) {
      float2 xv0 = xs[rowbase + 0][kk];
      float2 xv1 = xs[rowbase + 1][kk];
      float2 xv2 = xs[rowbase + 2][kk];
      float2 xv3 = xs[rowbase + 3][kk];
#pragma unroll
      for (int j = 0; j < 25; j++) {
        float2 wv = wsm[c0 + j][kk];
        acc[0][j] = fmaf(xv0.y, wv.y, fmaf(xv0.x, wv.x, acc[0][j]));
        acc[1][j] = fmaf(xv1.y, wv.y, fmaf(xv1.x, wv.x, acc[1][j]));
        acc[2][j] = fmaf(xv2.y, wv.y, fmaf(xv2.x, wv.x, acc[2][j]));
        acc[3][j] = fmaf(xv3.y, wv.y, fmaf(xv3.x, wv.x, acc[3][j]));
      }
    }
  }
#pragma unroll
  for (int rr = 0; rr < 4; rr++) {
    float* o = pre + (row0 + rowbase + rr) * 200 + c0;
#pragma unroll
    for (int j = 0; j < 25; j++) o[j] = acc[rr][j] + bsum[c0 + j];
  }
}

// ---------------- K2: recurrence over b (256 steps); 2 waves per (t,dir) chain.
// Wave0 computes h[0..63], wave1 h[64..99]; h exchanged via double-buffered LDS,
// one barrier per step. 2048 waves total -> 2 waves/SIMD (latency hiding).
__global__ __launch_bounds__(128, 2) void k_rnn(
    float* __restrict__ pre,
    const float* __restrict__ whf, const float* __restrict__ whb) {
  __shared__ float hx[2][104];
  int bid = blockIdx.x;
  int dir = bid >> 9;
  int t = bid & 511;
  const float* w = dir ? whb : whf;
  int tid = threadIdx.x;
  int wv = tid >> 6, lane = tid & 63;
  int row = wv ? (64 + (lane < 36 ? lane : 35)) : lane;
  bool owns = (!wv) || (lane < 36);
  float wr[HID_];
#pragma unroll
  for (int kk = 0; kk < 25; kk++) {
    float4 a4 = *(const float4*)(w + row * HID_ + 4 * kk);
    wr[4 * kk] = a4.x; wr[4 * kk + 1] = a4.y; wr[4 * kk + 2] = a4.z; wr[4 * kk + 3] = a4.w;
  }
  long step = dir ? -(long)(T_ * 200) : (long)(T_ * 200);
  float* p = pre + ((long)(dir ? (B_ - 1) : 0) * T_ + t) * 200 + dir * 100;
  if (tid < 104) hx[0][tid] = 0.f;
  float a = p[row];
  __syncthreads();
  for (int s = 0; s < B_; s++) {
    int cur = s & 1;
    float hA = hx[cur][lane];                            // h[0..63]
    float hB = hx[cur][64 + (lane < 36 ? lane : 35)];    // h[64..99] (bcast tail)
    float a_next = 0.f;
    if (s < B_ - 1) a_next = p[step + row];
    float ac0 = a, ac1 = 0.f, ac2 = 0.f, ac3 = 0.f;
#pragma unroll
    for (int k = 0; k < HID_; k++) {
      float hk = (k < 64) ? rl_f(hA, k) : rl_f(hB, k - 64);
      if ((k & 3) == 0)      ac0 = fmaf(hk, wr[k], ac0);
      else if ((k & 3) == 1) ac1 = fmaf(hk, wr[k], ac1);
      else if ((k & 3) == 2) ac2 = fmaf(hk, wr[k], ac2);
      else                   ac3 = fmaf(hk, wr[k], ac3);
    }
    float hnew = tanhf((ac0 + ac1) + (ac2 + ac3));
    if (owns) {
      p[row] = hnew;
      hx[cur ^ 1][row] = hnew;
    }
    p += step;
    a = a_next;
    __syncthreads();
  }
}

// ---------------- K3: logits = h @ w_lin^T + b_lin ; softmax over 19. 2 rows/thread.
__global__ __launch_bounds__(256, 4) void k_lin(
    const float* __restrict__ h, const float* __restrict__ wlin,
    const float* __restrict__ blin, float* __restrict__ em) {
  int tid = threadIdx.x;
  long r0 = ((long)blockIdx.x * 256 + tid) * 2;
  const float* h0 = h + r0 * 200;
  float acc0[K_], acc1[K_];
#pragma unroll
  for (int c = 0; c < K_; c++) { float bb = blin[c]; acc0[c] = bb; acc1[c] = bb; }
  for (int kk = 0; kk < 50; kk++) {
    float4 a = *(const float4*)(h0 + 4 * kk);
    float4 b = *(const float4*)(h0 + 200 + 4 * kk);
#pragma unroll
    for (int c = 0; c < K_; c++) {
      float4 wv = *(const float4*)(wlin + c * 200 + 4 * kk);  // uniform -> s_load
      acc0[c] += a.x * wv.x + a.y * wv.y + a.z * wv.z + a.w * wv.w;
      acc1[c] += b.x * wv.x + b.y * wv.y + b.z * wv.z + b.w * wv.w;
    }
  }
  float mx0 = acc0[0], mx1 = acc1[0];
#pragma unroll
  for (int c = 1; c < K_; c++) { mx0 = fmaxf(mx0, acc0[c]); mx1 = fmaxf(mx1, acc1[c]); }
  float s0 = 0.f, s1 = 0.f;
#pragma unroll
  for (int c = 0; c < K_; c++) {
    acc0[c] = __expf(acc0[c] - mx0); s0 += acc0[c];
    acc1[c] = __expf(acc1[c] - mx1); s1 += acc1[c];
  }
  float i0 = 1.f / s0, i1 = 1.f / s1;
  float* e0 = em + r0 * K_;
#pragma unroll
  for (int c = 0; c < K_; c++) { e0[c] = acc0[c] * i0; e0[K_ + c] = acc1[c] * i1; }
}

// ---------------- K4: per-b CRF logZ + gold score (wave0) | Viterbi fwd + backtrack (wave1)
__global__ __launch_bounds__(128, 1) void k_crf(
    const float* __restrict__ em, const int* __restrict__ y,
    const float* __restrict__ st_g, const float* __restrict__ en_g,
    const float* __restrict__ tr_g,
    float* __restrict__ part, int* __restrict__ cnt,
    float* __restrict__ out) {
  __shared__ __align__(16) float es[T_ * K_];
  __shared__ int ys[T_];
  __shared__ float tr[K_ * K_];
  __shared__ float st[K_], en[K_];
  __shared__ unsigned char hl[511 * K_ + 13];
  __shared__ float lab[T_];
  int b = blockIdx.x;
  int tid = threadIdx.x;
  const float4* eb4 = (const float4*)(em + (long)b * T_ * K_);
  for (int u = tid; u < T_ * K_ / 4; u += 128) ((float4*)es)[u] = eb4[u];
  for (int u = tid; u < T_; u += 128) ys[u] = y[b * T_ + u];
  for (int u = tid; u < K_ * K_; u += 128) tr[u] = tr_g[u];
  if (tid < K_) { st[tid] = st_g[tid]; en[tid] = en_g[tid]; }
  __syncthreads();
  int wv = tid >> 6, lane = tid & 63;
  int jj = lane < K_ ? lane : K_ - 1;
  bool act = lane < K_;
  if (wv == 0) {
    float E[K_];
#pragma unroll
    for (int i = 0; i < K_; i++) E[i] = __expf(tr[i * K_ + jj]);
    float z = act ? st[jj] + es[jj] : -1e30f;
    int y0 = ys[0];
    int prev = (y0 != -1) ? y0 : 0;
    float num = st[prev] + es[prev];
    for (int t = 1; t < T_; t++) {
      float e = es[t * K_ + jj];
      int yv = ys[t];
      bool mb = (yv != -1);
      float m = z;
#pragma unroll
      for (int off = 16; off; off >>= 1) m = fmaxf(m, __shfl_xor(m, off, 32));
      float pz = __expf(z - m);
      float acca = 0.f, accb = 0.f;
#pragma unroll
      for (int i = 0; i < 9; i++)  acca = fmaf(rl_f(pz, i), E[i], acca);
#pragma unroll
      for (int i = 9; i < K_; i++) accb = fmaf(rl_f(pz, i), E[i], accb);
      float nz = e + m + __logf(acca + accb);
      if (act && mb) z = nz;
      if (mb) {
        num += tr[prev * K_ + yv] + es[t * K_ + yv];
        prev = yv;
      }
    }
    num += en[prev];
    float zf = z + en[jj];
    float m2 = zf;
#pragma unroll
    for (int off = 16; off; off >>= 1) m2 = fmaxf(m2, __shfl_xor(m2, off, 32));
    float sm = __expf(zf - m2);
#pragma unroll
    for (int off = 16; off; off >>= 1) sm += __shfl_xor(sm, off, 32);
    if (lane == 0) part[b] = m2 + __logf(sm) - num;
  } else {
    float Tt[K_];
#pragma unroll
    for (int i = 0; i < K_; i++) Tt[i] = tr[i * K_ + jj];
    float v = act ? st[jj] + es[jj] : -1e30f;
    for (int t = 1; t < T_; t++) {
      float e = es[t * K_ + jj];
      int yv = ys[t];
      bool mb = (yv != -1);
      float b0 = -1e30f, b1 = -1e30f, b2 = -1e30f, b3 = -1e30f;
      int a0 = 0, a1 = 5, a2 = 10, a3 = 15;
#pragma unroll
      for (int i = 0; i < 5; i++)  { float c = rl_f(v, i) + Tt[i]; if (c > b0) { b0 = c; a0 = i; } }
#pragma unroll
      for (int i = 5; i < 10; i++) { float c = rl_f(v, i) + Tt[i]; if (c > b1) { b1 = c; a1 = i; } }
#pragma unroll
      for (int i = 10; i < 15; i++){ float c = rl_f(v, i) + Tt[i]; if (c > b2) { b2 = c; a2 = i; } }
#pragma unroll
      for (int i = 15; i < 19; i++){ float c = rl_f(v, i) + Tt[i]; if (c > b3) { b3 = c; a3 = i; } }
      if (b1 > b0) { b0 = b1; a0 = a1; }
      if (b2 > b0) { b0 = b2; a0 = a2; }
      if (b3 > b0) { b0 = b3; a0 = a3; }
      if (act) hl[(t - 1) * K_ + lane] = (unsigned char)a0;
      if (act && mb) v = b0 + e;
    }
    float sc = v + en[jj];
    float bb = -1e30f; int aa = 0;
#pragma unroll
    for (int i = 0; i < K_; i++) { float c = rl_f(sc, i); if (c > bb) { bb = c; aa = i; } }
    int tag = aa;
    if (lane == 0) lab[T_ - 1] = (ys[T_ - 1] != -1) ? (float)tag : -1.f;
    int vc = (lane < K_) ? (int)hl[510 * K_ + lane] : 0;
    for (int ti = 510; ti >= 0; ti--) {
      int vn = 0;
      if (ti > 0 && lane < K_) vn = (int)hl[(ti - 1) * K_ + lane];
      int ts = __builtin_amdgcn_readfirstlane(tag);
      int cand = __builtin_amdgcn_readlane(vc, ts);
      tag = (ys[ti + 1] != -1) ? cand : tag;
      if (lane == 0) lab[ti] = (ys[ti] != -1) ? (float)tag : -1.f;
      vc = vn;
    }
  }
  __syncthreads();
  if (wv == 1) {
    float* ob = out + 1 + (long)b * T_;
    for (int u = lane; u < T_; u += 64) ob[u] = lab[u];
  } else {
    int old = -1;
    if (lane == 0) { __threadfence(); old = atomicAdd(cnt, 1); }
    old = __shfl(old, 0, 64);
    if (old == B_ - 1) {  // last block: deterministic fixed-order sum
      __threadfence();
      float s = 0.f;
      for (int u = lane; u < B_; u += 64) s += part[u];
#pragma unroll
      for (int off = 32; off; off >>= 1) s += __shfl_xor(s, off, 64);
      if (lane == 0) out[0] = s;
    }
  }
}

extern "C" void kernel_launch(void* const* d_in, const int* in_sizes, int n_in,
                              void* d_out, int out_size, void* d_ws, size_t ws_size,
                              hipStream_t stream) {
  const float* x      = (const float*)d_in[0];
  const int*   y      = (const int*)d_in[1];
  const float* w_ih_f = (const float*)d_in[2];
  const float* w_hh_f = (const float*)d_in[3];
  const float* b_ih_f = (const float*)d_in[4];
  const float* b_hh_f = (const float*)d_in[5];
  const float* w_ih_b = (const float*)d_in[6];
  const float* w_hh_b = (const float*)d_in[7];
  const float* b_ih_b = (const float*)d_in[8];
  const float* b_hh_b = (const float*)d_in[9];
  const float* w_lin  = (const float*)d_in[10];
  const float* b_lin  = (const float*)d_in[11];
  const float* st     = (const float*)d_in[12];
  const float* en     = (const float*)d_in[13];
  const float* trans  = (const float*)d_in[14];

  char* ws = (char*)d_ws;
  const size_t PRE_OFF  = 0;                          // 131072*200*4 = 104857600
  const size_t EM_OFF   = 104857600;                  // 131072*19*4  = 9961472
  const size_t PART_OFF = EM_OFF + 9961472;           // 1024
  const size_t CNT_OFF  = PART_OFF + 1024;            // 4
  float* PRE  = (float*)(ws + PRE_OFF);
  float* EM   = (float*)(ws + EM_OFF);
  float* PART = (float*)(ws + PART_OFF);
  int*   CNT  = (int*)(ws + CNT_OFF);
  float* out  = (float*)d_out;

  hipMemsetAsync((void*)CNT, 0, sizeof(int), stream);
  k_ih<<<1024, 256, 0, stream>>>(x, w_ih_f, w_ih_b, b_ih_f, b_hh_f, b_ih_b, b_hh_b, PRE);
  k_rnn<<<1024, 128, 0, stream>>>(PRE, w_hh_f, w_hh_b);
  k_lin<<<256, 256, 0, stream>>>(PRE, w_lin, b_lin, EM);
  k_crf<<<256, 128, 0, stream>>>(EM, y, st, en, trans, PART, CNT, out);
}

// Round 5
// 723.960 us; speedup vs baseline: 2.8968x; 1.1036x over previous
//
#include <hip/hip_runtime.h>
#include <hip/hip_bf16.h>

#define B_ 256
#define T_ 512
#define IN_ 202
#define HID_ 100
#define K_ 19

__device__ __forceinline__ float rl_f(float v, int l) {
  return __int_as_float(__builtin_amdgcn_readlane(__float_as_int(v), l));
}

// ---------------- K1: pre[row*200 + c] = x . [wf;wb]^T + bias, both dirs fused.
__global__ __launch_bounds__(256, 2) void k_ih(
    const float* __restrict__ x,
    const float* __restrict__ wf, const float* __restrict__ wb,
    const float* __restrict__ bif, const float* __restrict__ bhf,
    const float* __restrict__ bib, const float* __restrict__ bhb,
    float* __restrict__ pre) {
  __shared__ float2 xs[128][17];   // [row][kpair], stride 17 f2 = 34 f -> conflict-free reads
  __shared__ float2 wsm[200][17];  // [col][kpair]
  __shared__ float bsum[200];
  int tid = threadIdx.x;
  int cg = tid & 7, rg = tid >> 3;
  int c0 = cg * 25;
  int rowbase = rg * 4;
  long row0 = (long)blockIdx.x * 128;
  for (int u = tid; u < 200; u += 256)
    bsum[u] = (u < 100) ? (bif[u] + bhf[u]) : (bib[u - 100] + bhb[u - 100]);
  float acc[4][25];
#pragma unroll
  for (int r = 0; r < 4; r++)
#pragma unroll
    for (int j = 0; j < 25; j++) acc[r][j] = 0.f;

  for (int ck = 0; ck < 7; ck++) {
    int k0 = ck * 32;
    __syncthreads();
    for (int u = tid; u < 2048; u += 256) {
      int r = u >> 4, kp = u & 15;
      int gk = k0 + 2 * kp;
      float2 v = make_float2(0.f, 0.f);
      if (gk < IN_) v = *(const float2*)(x + (row0 + r) * IN_ + gk);
      xs[r][kp] = v;
    }
    for (int u = tid; u < 3200; u += 256) {
      int c = u >> 4, kp = u & 15;
      int gk = k0 + 2 * kp;
      float2 v = make_float2(0.f, 0.f);
      if (gk < IN_) {
        const float* src = (c < 100) ? (wf + c * IN_) : (wb + (c - 100) * IN_);
        v = *(const float2*)(src + gk);
      }
      wsm[c][kp] = v;
    }
    __syncthreads();
#pragma unroll 4
    for (int kk = 0; kk < 16; kk++) {
      float2 xv0 = xs[rowbase + 0][kk];
      float2 xv1 = xs[rowbase + 1][kk];
      float2 xv2 = xs[rowbase + 2][kk];
      float2 xv3 = xs[rowbase + 3][kk];
#pragma unroll
      for (int j = 0; j < 25; j++) {
        float2 wv = wsm[c0 + j][kk];
        acc[0][j] = fmaf(xv0.y, wv.y, fmaf(xv0.x, wv.x, acc[0][j]));
        acc[1][j] = fmaf(xv1.y, wv.y, fmaf(xv1.x, wv.x, acc[1][j]));
        acc[2][j] = fmaf(xv2.y, wv.y, fmaf(xv2.x, wv.x, acc[2][j]));
        acc[3][j] = fmaf(xv3.y, wv.y, fmaf(xv3.x, wv.x, acc[3][j]));
      }
    }
  }
#pragma unroll
  for (int rr = 0; rr < 4; rr++) {
    float* o = pre + (row0 + rowbase + rr) * 200 + c0;
#pragma unroll
    for (int j = 0; j < 25; j++) o[j] = acc[rr][j] + bsum[c0 + j];
  }
}

// ---------------- K2: recurrence over b (256 steps); 4 waves per (t,dir) chain.
// Waves {0,1} own rows 0..63, waves {2,3} own rows 64..99; within a pair waves
// take k-slices [0,52) / [52,100). h broadcast via uniform ds_read_b128 (no
// readlane->SGPR hazard); partials exchanged in LDS; 2 barriers/step.
// 1024 blocks x 4 waves = 4096 waves -> 4 waves/SIMD.
template <int KO, int KN, bool OW>
__device__ __forceinline__ void rnn_loop(
    float* __restrict__ p, long step, int row, bool owns,
    const float* __restrict__ w, float (*hb)[104], float* __restrict__ ps) {
  float wr[KN];
#pragma unroll
  for (int i = 0; i < KN / 4; i++) {
    float4 w4 = *(const float4*)(w + row * HID_ + KO + 4 * i);
    wr[4 * i + 0] = w4.x; wr[4 * i + 1] = w4.y;
    wr[4 * i + 2] = w4.z; wr[4 * i + 3] = w4.w;
  }
  float a = 0.f;
  if (OW) a = p[row];
  for (int s = 0; s < B_; s++) {
    int cur = s & 1;
    float a_next = 0.f;
    if (OW && s < B_ - 1) a_next = p[step + row];
    float ac0 = OW ? a : 0.f, ac1 = 0.f, ac2 = 0.f, ac3 = 0.f;
#pragma unroll
    for (int i = 0; i < KN / 4; i++) {
      float4 h4 = *(const float4*)(&hb[cur][KO + 4 * i]);  // uniform addr -> broadcast
      ac0 = fmaf(h4.x, wr[4 * i + 0], ac0);
      ac1 = fmaf(h4.y, wr[4 * i + 1], ac1);
      ac2 = fmaf(h4.z, wr[4 * i + 2], ac2);
      ac3 = fmaf(h4.w, wr[4 * i + 3], ac3);
    }
    float partial = (ac0 + ac1) + (ac2 + ac3);
    if (!OW && owns) ps[row] = partial;
    __syncthreads();
    if (OW) {
      float hnew = tanhf(partial + ps[row]);
      if (owns) {
        hb[cur ^ 1][row] = hnew;
        p[row] = hnew;
      }
    }
    p += step;
    a = a_next;
    __syncthreads();
  }
}

__global__ __launch_bounds__(256, 4) void k_rnn(
    float* __restrict__ pre,
    const float* __restrict__ whf, const float* __restrict__ whb) {
  __shared__ float hb[2][104];
  __shared__ float ps[104];
  int bid = blockIdx.x;
  int dir = bid >> 9;
  int t = bid & 511;
  const float* w = dir ? whb : whf;
  int tid = threadIdx.x;
  int wv = tid >> 6, lane = tid & 63;
  int grp = wv >> 1;     // 0: rows 0..63, 1: rows 64..99
  int khalf = wv & 1;    // 0: k 0..51 (owner), 1: k 52..99
  int row = grp ? (64 + (lane < 36 ? lane : 35)) : lane;
  bool owns = grp ? (lane < 36) : true;
  long step = dir ? -(long)(T_ * 200) : (long)(T_ * 200);
  float* p = pre + ((long)(dir ? (B_ - 1) : 0) * T_ + t) * 200 + dir * 100;
  if (tid < 104) hb[0][tid] = 0.f;
  __syncthreads();
  if (khalf == 0) rnn_loop<0, 52, true >(p, step, row, owns, w, hb, ps);
  else            rnn_loop<52, 48, false>(p, step, row, owns, w, hb, ps);
}

// ---------------- K3: logits = h @ w_lin^T + b_lin ; softmax over 19. 2 rows/thread.
__global__ __launch_bounds__(256, 4) void k_lin(
    const float* __restrict__ h, const float* __restrict__ wlin,
    const float* __restrict__ blin, float* __restrict__ em) {
  int tid = threadIdx.x;
  long r0 = ((long)blockIdx.x * 256 + tid) * 2;
  const float* h0 = h + r0 * 200;
  float acc0[K_], acc1[K_];
#pragma unroll
  for (int c = 0; c < K_; c++) { float bb = blin[c]; acc0[c] = bb; acc1[c] = bb; }
  for (int kk = 0; kk < 50; kk++) {
    float4 a = *(const float4*)(h0 + 4 * kk);
    float4 b = *(const float4*)(h0 + 200 + 4 * kk);
#pragma unroll
    for (int c = 0; c < K_; c++) {
      float4 wv = *(const float4*)(wlin + c * 200 + 4 * kk);  // uniform -> s_load
      acc0[c] += a.x * wv.x + a.y * wv.y + a.z * wv.z + a.w * wv.w;
      acc1[c] += b.x * wv.x + b.y * wv.y + b.z * wv.z + b.w * wv.w;
    }
  }
  float mx0 = acc0[0], mx1 = acc1[0];
#pragma unroll
  for (int c = 1; c < K_; c++) { mx0 = fmaxf(mx0, acc0[c]); mx1 = fmaxf(mx1, acc1[c]); }
  float s0 = 0.f, s1 = 0.f;
#pragma unroll
  for (int c = 0; c < K_; c++) {
    acc0[c] = __expf(acc0[c] - mx0); s0 += acc0[c];
    acc1[c] = __expf(acc1[c] - mx1); s1 += acc1[c];
  }
  float i0 = 1.f / s0, i1 = 1.f / s1;
  float* e0 = em + r0 * K_;
#pragma unroll
  for (int c = 0; c < K_; c++) { e0[c] = acc0[c] * i0; e0[K_ + c] = acc1[c] * i1; }
}

// ---------------- K4: per-b CRF logZ + gold score (wave0) | Viterbi fwd + backtrack (wave1)
__global__ __launch_bounds__(128, 1) void k_crf(
    const float* __restrict__ em, const int* __restrict__ y,
    const float* __restrict__ st_g, const float* __restrict__ en_g,
    const float* __restrict__ tr_g,
    float* __restrict__ part, int* __restrict__ cnt,
    float* __restrict__ out) {
  __shared__ __align__(16) float es[T_ * K_];
  __shared__ int ys[T_];
  __shared__ float tr[K_ * K_];
  __shared__ float st[K_], en[K_];
  __shared__ unsigned char hl[511 * K_ + 13];
  __shared__ float lab[T_];
  int b = blockIdx.x;
  int tid = threadIdx.x;
  const float4* eb4 = (const float4*)(em + (long)b * T_ * K_);
  for (int u = tid; u < T_ * K_ / 4; u += 128) ((float4*)es)[u] = eb4[u];
  for (int u = tid; u < T_; u += 128) ys[u] = y[b * T_ + u];
  for (int u = tid; u < K_ * K_; u += 128) tr[u] = tr_g[u];
  if (tid < K_) { st[tid] = st_g[tid]; en[tid] = en_g[tid]; }
  __syncthreads();
  int wv = tid >> 6, lane = tid & 63;
  int jj = lane < K_ ? lane : K_ - 1;
  bool act = lane < K_;
  if (wv == 0) {
    float E[K_];
#pragma unroll
    for (int i = 0; i < K_; i++) E[i] = __expf(tr[i * K_ + jj]);
    float z = act ? st[jj] + es[jj] : -1e30f;
    int y0 = ys[0];
    int prev = (y0 != -1) ? y0 : 0;
    float num = st[prev] + es[prev];
    for (int t = 1; t < T_; t++) {
      float e = es[t * K_ + jj];
      int yv = ys[t];
      bool mb = (yv != -1);
      float m = z;
#pragma unroll
      for (int off = 16; off; off >>= 1) m = fmaxf(m, __shfl_xor(m, off, 32));
      float pz = __expf(z - m);
      float acca = 0.f, accb = 0.f;
#pragma unroll
      for (int i = 0; i < 9; i++)  acca = fmaf(rl_f(pz, i), E[i], acca);
#pragma unroll
      for (int i = 9; i < K_; i++) accb = fmaf(rl_f(pz, i), E[i], accb);
      float nz = e + m + __logf(acca + accb);
      if (act && mb) z = nz;
      if (mb) {
        num += tr[prev * K_ + yv] + es[t * K_ + yv];
        prev = yv;
      }
    }
    num += en[prev];
    float zf = z + en[jj];
    float m2 = zf;
#pragma unroll
    for (int off = 16; off; off >>= 1) m2 = fmaxf(m2, __shfl_xor(m2, off, 32));
    float sm = __expf(zf - m2);
#pragma unroll
    for (int off = 16; off; off >>= 1) sm += __shfl_xor(sm, off, 32);
    if (lane == 0) part[b] = m2 + __logf(sm) - num;
  } else {
    float Tt[K_];
#pragma unroll
    for (int i = 0; i < K_; i++) Tt[i] = tr[i * K_ + jj];
    float v = act ? st[jj] + es[jj] : -1e30f;
    for (int t = 1; t < T_; t++) {
      float e = es[t * K_ + jj];
      int yv = ys[t];
      bool mb = (yv != -1);
      float b0 = -1e30f, b1 = -1e30f, b2 = -1e30f, b3 = -1e30f;
      int a0 = 0, a1 = 5, a2 = 10, a3 = 15;
#pragma unroll
      for (int i = 0; i < 5; i++)  { float c = rl_f(v, i) + Tt[i]; if (c > b0) { b0 = c; a0 = i; } }
#pragma unroll
      for (int i = 5; i < 10; i++) { float c = rl_f(v, i) + Tt[i]; if (c > b1) { b1 = c; a1 = i; } }
#pragma unroll
      for (int i = 10; i < 15; i++){ float c = rl_f(v, i) + Tt[i]; if (c > b2) { b2 = c; a2 = i; } }
#pragma unroll
      for (int i = 15; i < 19; i++){ float c = rl_f(v, i) + Tt[i]; if (c > b3) { b3 = c; a3 = i; } }
      if (b1 > b0) { b0 = b1; a0 = a1; }
      if (b2 > b0) { b0 = b2; a0 = a2; }
      if (b3 > b0) { b0 = b3; a0 = a3; }
      if (act) hl[(t - 1) * K_ + lane] = (unsigned char)a0;
      if (act && mb) v = b0 + e;
    }
    float sc = v + en[jj];
    float bb = -1e30f; int aa = 0;
#pragma unroll
    for (int i = 0; i < K_; i++) { float c = rl_f(sc, i); if (c > bb) { bb = c; aa = i; } }
    int tag = aa;
    if (lane == 0) lab[T_ - 1] = (ys[T_ - 1] != -1) ? (float)tag : -1.f;
    int vc = (lane < K_) ? (int)hl[510 * K_ + lane] : 0;
    for (int ti = 510; ti >= 0; ti--) {
      int vn = 0;
      if (ti > 0 && lane < K_) vn = (int)hl[(ti - 1) * K_ + lane];
      int ts = __builtin_amdgcn_readfirstlane(tag);
      int cand = __builtin_amdgcn_readlane(vc, ts);
      tag = (ys[ti + 1] != -1) ? cand : tag;
      if (lane == 0) lab[ti] = (ys[ti] != -1) ? (float)tag : -1.f;
      vc = vn;
    }
  }
  __syncthreads();
  if (wv == 1) {
    float* ob = out + 1 + (long)b * T_;
    for (int u = lane; u < T_; u += 64) ob[u] = lab[u];
  } else {
    int old = -1;
    if (lane == 0) { __threadfence(); old = atomicAdd(cnt, 1); }
    old = __shfl(old, 0, 64);
    if (old == B_ - 1) {  // last block: deterministic fixed-order sum
      __threadfence();
      float s = 0.f;
      for (int u = lane; u < B_; u += 64) s += part[u];
#pragma unroll
      for (int off = 32; off; off >>= 1) s += __shfl_xor(s, off, 64);
      if (lane == 0) out[0] = s;
    }
  }
}

extern "C" void kernel_launch(void* const* d_in, const int* in_sizes, int n_in,
                              void* d_out, int out_size, void* d_ws, size_t ws_size,
                              hipStream_t stream) {
  const float* x      = (const float*)d_in[0];
  const int*   y      = (const int*)d_in[1];
  const float* w_ih_f = (const float*)d_in[2];
  const float* w_hh_f = (const float*)d_in[3];
  const float* b_ih_f = (const float*)d_in[4];
  const float* b_hh_f = (const float*)d_in[5];
  const float* w_ih_b = (const float*)d_in[6];
  const float* w_hh_b = (const float*)d_in[7];
  const float* b_ih_b = (const float*)d_in[8];
  const float* b_hh_b = (const float*)d_in[9];
  const float* w_lin  = (const float*)d_in[10];
  const float* b_lin  = (const float*)d_in[11];
  const float* st     = (const float*)d_in[12];
  const float* en     = (const float*)d_in[13];
  const float* trans  = (const float*)d_in[14];

  char* ws = (char*)d_ws;
  const size_t PRE_OFF  = 0;                          // 131072*200*4 = 104857600
  const size_t EM_OFF   = 104857600;                  // 131072*19*4  = 9961472
  const size_t PART_OFF = EM_OFF + 9961472;           // 1024
  const size_t CNT_OFF  = PART_OFF + 1024;            // 4
  float* PRE  = (float*)(ws + PRE_OFF);
  float* EM   = (float*)(ws + EM_OFF);
  float* PART = (float*)(ws + PART_OFF);
  int*   CNT  = (int*)(ws + CNT_OFF);
  float* out  = (float*)d_out;

  hipMemsetAsync((void*)CNT, 0, sizeof(int), stream);
  k_ih<<<1024, 256, 0, stream>>>(x, w_ih_f, w_ih_b, b_ih_f, b_hh_f, b_ih_b, b_hh_b, PRE);
  k_rnn<<<1024, 256, 0, stream>>>(PRE, w_hh_f, w_hh_b);
  k_lin<<<256, 256, 0, stream>>>(PRE, w_lin, b_lin, EM);
  k_crf<<<256, 128, 0, stream>>>(EM, y, st, en, trans, PART, CNT, out);
}